// Round 10
// baseline (202.901 us; speedup 1.0000x reference)
//
#include <hip/hip_runtime.h>
#include <cstdint>
#include <cstddef>

typedef __attribute__((ext_vector_type(8))) short bf16x8;
typedef __attribute__((ext_vector_type(4))) unsigned short u16x4;
typedef __attribute__((ext_vector_type(4))) unsigned u32x4;
typedef __attribute__((ext_vector_type(4))) float f32x4;
typedef unsigned short u16;

#define T_TOT 9728
#define DDIM  2048
#define GHN   256
#define NSEQ  8

__device__ __constant__ int OFFS[NSEQ + 1] = {0, 512, 1536, 3072, 5120, 5760, 6656, 7936, 9728};

__device__ __forceinline__ u16 f2bf(float f) {
  union { float f; unsigned u; } v; v.f = f;
  unsigned r = v.u + 0x7FFFu + ((v.u >> 16) & 1u);
  return (u16)(r >> 16);
}
__device__ __forceinline__ float silu_f(float v) {
  return v / (1.0f + __expf(-v));
}

// Pin a 128-bit value into regs: volatile asm can't be duplicated, so the
// compiler cannot rematerialize the originating load inside later loops.
__device__ __forceinline__ void pin_reg(bf16x8& v) {
  u32x4& u = reinterpret_cast<u32x4&>(v);
  asm volatile("" : "+v"(u));
}

// async global->LDS, 16B per lane, wave-uniform LDS base + lane*16 (m97 pattern)
__device__ __forceinline__ void gload_lds16(const u16* src, u16* dst) {
  __builtin_amdgcn_global_load_lds(
      (__attribute__((address_space(1))) void*)src,
      (__attribute__((address_space(3))) void*)dst,
      16, 0, 0);
}

// ---------------------------------------------------------------------------
// Prep: fp32 [R][C] -> bf16 [C][R]  (transpose + convert), 64x64 tiles
// ---------------------------------------------------------------------------
__global__ __launch_bounds__(256)
void transpose_bf16_k(const float* __restrict__ in, u16* __restrict__ out, int R, int C) {
  __shared__ float tile[64][65];
  const int c0 = blockIdx.x * 64, r0 = blockIdx.y * 64;
  const int tid = threadIdx.x;
  const int lc = tid & 63, lr = tid >> 6;
#pragma unroll
  for (int p = 0; p < 16; ++p) {
    int r = lr + p * 4;
    tile[r][lc] = in[(size_t)(r0 + r) * C + c0 + lc];
  }
  __syncthreads();
#pragma unroll
  for (int p = 0; p < 16; ++p) {
    int c = lr + p * 4;
    out[(size_t)(c0 + c) * R + r0 + lc] = f2bf(tile[lc][c]);
  }
}

// ---------------------------------------------------------------------------
// Kernel A: h = silu(gi @ w1)  (validated; h stored PRE-SWIZZLED:
// element (t,c) at t*256 + ((c>>3)^(t&7))*8 + (c&7))
// ---------------------------------------------------------------------------
__global__ __launch_bounds__(256, 4)
void gemm1_silu(const float* __restrict__ gi, const u16* __restrict__ w1T,
                u16* __restrict__ h) {
  __shared__ u16 A[32][72];
  const int tid = threadIdx.x;
  const int lane = tid & 63, wid = tid >> 6;
  const int l15 = lane & 15, l4 = lane >> 4;
  const int t0 = blockIdx.x * 32;
  const int nb = wid * 64;

  f32x4 acc[2][4] = {};

  for (int k0 = 0; k0 < DDIM; k0 += 64) {
#pragma unroll
    for (int j = 0; j < 2; ++j) {
      int idx = tid + j * 256;
      int m = idx >> 4, f4 = idx & 15;
      f32x4 v = *reinterpret_cast<const f32x4*>(&gi[(size_t)(t0 + m) * DDIM + k0 + f4 * 4]);
      u16x4 b;
      b[0] = f2bf(v[0]); b[1] = f2bf(v[1]); b[2] = f2bf(v[2]); b[3] = f2bf(v[3]);
      *reinterpret_cast<u16x4*>(&A[m][f4 * 4]) = b;
    }
    __syncthreads();
#pragma unroll
    for (int ks = 0; ks < 2; ++ks) {
      bf16x8 af[2], bfr[4];
#pragma unroll
      for (int mi = 0; mi < 2; ++mi)
        af[mi] = *reinterpret_cast<const bf16x8*>(&A[mi * 16 + l15][ks * 32 + 8 * l4]);
#pragma unroll
      for (int ni = 0; ni < 4; ++ni)
        bfr[ni] = *reinterpret_cast<const bf16x8*>(
            &w1T[(size_t)(nb + ni * 16 + l15) * DDIM + k0 + ks * 32 + 8 * l4]);
#pragma unroll
      for (int mi = 0; mi < 2; ++mi)
#pragma unroll
        for (int ni = 0; ni < 4; ++ni)
          acc[mi][ni] = __builtin_amdgcn_mfma_f32_16x16x32_bf16(af[mi], bfr[ni], acc[mi][ni], 0, 0, 0);
    }
    __syncthreads();
  }

#pragma unroll
  for (int mi = 0; mi < 2; ++mi)
#pragma unroll
    for (int ni = 0; ni < 4; ++ni)
#pragma unroll
      for (int r = 0; r < 4; ++r) {
        float v = silu_f(acc[mi][ni][r]);
        int token = t0 + mi * 16 + l4 * 4 + r;
        int c = nb + ni * 16 + l15;
        int pos = ((((c >> 3) ^ (token & 7)) << 3) | (c & 7));
        h[(size_t)token * GHN + pos] = f2bf(v);
      }
}

// ---------------------------------------------------------------------------
// Kernel B: fused kern = h@w2+b2 -> 4-tap conv -> silu -> out.
// grid (38 tg, 128 col-tiles of 64); 256 thr / 4 waves; wave owns 16 cols
// (4 channels, IDENTITY col map). bw[8]=32 regs pinned; acc[4]=16.
// ~118 regs/wave -> 3 blocks/CU (LDS-limited), occupancy 37.5%.
// 2 barriers/chunk: GEMM | barA | stage-issue + conv->Ot[p] | barC | store.
// Ot double-buffered [2][64][19] f32 (write conflict-free, read ~2-way).
// Conv: tap k=l15&3 lane-local, 4-lane shfl_xor(1)+(2) reduce, no LDS exch.
// ---------------------------------------------------------------------------
__global__ __launch_bounds__(256, 3)
void gemm2_conv(const u16* __restrict__ h, const u16* __restrict__ w2T,
                const float* __restrict__ b2, const float* __restrict__ x,
                const float* __restrict__ cs, float* __restrict__ out) {
  __shared__ u16 H[64 * 256];        // 32KB single buffer
  __shared__ float Ot[2][64 * 19];   // 2 x 4.75KB out-staging
  const int tid = threadIdx.x;
  const int lane = tid & 63, wid = tid >> 6;
  const int l15 = lane & 15, l4 = lane >> 4;
  const int d0 = blockIdx.y * 16;              // block's 16 channels
  const int colwave = blockIdx.y * 64 + wid * 16;  // wave's 16 kern cols
  const int tg = blockIdx.x;

  // w2 fragments: load once (identity col map), then PIN
  bf16x8 bw[8];
#pragma unroll
  for (int ks = 0; ks < 8; ++ks)
    bw[ks] = *reinterpret_cast<const bf16x8*>(
        w2T + (size_t)(colwave + l15) * GHN + ks * 32 + l4 * 8);
#pragma unroll
  for (int ks = 0; ks < 8; ++ks) pin_reg(bw[ks]);

  const float b2v = b2[colwave + l15];

  const int c = l15 >> 2, k = l15 & 3;  // channel-in-wave, tap
  const int d = d0 + wid * 4 + c;       // this lane's conv channel
  const int dloc = wid * 4 + c;         // channel within block (0..15)

  // prologue: stage chunk 0 (linear dest: h is pre-swizzled)
  {
    const u16* hb = h + (size_t)(tg * 4) * 64 * GHN;
#pragma unroll
    for (int p = 0; p < 8; ++p)
      gload_lds16(hb + (size_t)(p * 256 + tid) * 8, &H[(p * 256 + tid) * 8]);
  }
  __syncthreads();

  int pbuf = 0;
  for (int it = 0; it < 4; ++it) {
    const int t0 = (tg * 4 + it) * 64;

    // ---- GEMM: 8 ks x (4 A-frag ds_read + 4 MFMA), B pinned ----
    f32x4 acc[4] = {};
#pragma unroll
    for (int ks = 0; ks < 8; ++ks) {
#pragma unroll
      for (int mi = 0; mi < 4; ++mi) {
        int m = mi * 16 + l15;
        int g = ks * 4 + l4;
        bf16x8 af = *reinterpret_cast<const bf16x8*>(&H[m * 256 + ((g ^ (m & 7)) << 3)]);
        acc[mi] = __builtin_amdgcn_mfma_f32_16x16x32_bf16(af, bw[ks], acc[mi], 0, 0, 0);
      }
    }

    __syncthreads();  // barA: all H reads complete (drains lgkm + prev stores)

    // issue next chunk's staging; flight hides under conv epilogue
    if (it < 3) {
      const u16* hb = h + (size_t)(t0 + 64) * GHN;
#pragma unroll
      for (int p = 0; p < 8; ++p)
        gload_lds16(hb + (size_t)(p * 256 + tid) * 8, &H[(p * 256 + tid) * 8]);
    }

    // ---- conv epilogue -> Ot[pbuf] ----
    int iseq = 0;
    while (OFFS[iseq + 1] <= t0) ++iseq;
    const int seq_start = OFFS[iseq];

#pragma unroll
    for (int mi = 0; mi < 4; ++mi) {
      const int base = t0 + mi * 16 + l4 * 4;
      // xw[j] = x(base + j + k - 3, d), j=0..3
      float xw0, xw1, xw2, xw3;
      {
        int s0 = base + k - 3;
        const float* xr = x + (size_t)s0 * DDIM + d;
        const float* cr = cs + ((size_t)iseq * DDIM + d) * 3 + (s0 - seq_start + 3);
        xw0 = (s0 >= seq_start) ? xr[0] : cr[0];
        xw1 = (s0 + 1 >= seq_start) ? xr[DDIM] : cr[1];
        xw2 = (s0 + 2 >= seq_start) ? xr[2 * DDIM] : cr[2];
        xw3 = (s0 + 3 >= seq_start) ? xr[3 * DDIM] : x[(size_t)(s0 + 3) * DDIM + d];
      }
      float p0 = (acc[mi][0] + b2v) * xw0;
      float p1 = (acc[mi][1] + b2v) * xw1;
      float p2 = (acc[mi][2] + b2v) * xw2;
      float p3 = (acc[mi][3] + b2v) * xw3;
      float t0r = p0 + __shfl_xor(p0, 1); t0r += __shfl_xor(t0r, 2);
      float t1r = p1 + __shfl_xor(p1, 1); t1r += __shfl_xor(t1r, 2);
      float t2r = p2 + __shfl_xor(p2, 1); t2r += __shfl_xor(t2r, 2);
      float t3r = p3 + __shfl_xor(p3, 1); t3r += __shfl_xor(t3r, 2);
      float val = t0r;
      val = (k == 1) ? t1r : val;
      val = (k == 2) ? t2r : val;
      val = (k == 3) ? t3r : val;
      Ot[pbuf][(mi * 16 + l4 * 4 + k) * 19 + dloc] = silu_f(val);
    }

    __syncthreads();  // barC: drains gload_lds vmcnt; publishes H & Ot[pbuf]

    // ---- coalesced store: 4 threads = one dense 64B token row ----
    {
      const int row = tid >> 2, tq = tid & 3;
      f32x4 o = *reinterpret_cast<const f32x4*>(&Ot[pbuf][row * 19 + tq * 4]);
      *reinterpret_cast<f32x4*>(out + (size_t)(t0 + row) * DDIM + d0 + tq * 4) = o;
    }
    pbuf ^= 1;
  }
}

// ---------------------------------------------------------------------------
// Kernel C: new_conv_state[i][d][m] = x[offs[i+1]-3+m][d]
// ---------------------------------------------------------------------------
__global__ __launch_bounds__(256)
void tail_state(const float* __restrict__ x, float* __restrict__ out2) {
  int idx = blockIdx.x * 256 + threadIdx.x;
  int i = idx / (DDIM * 3);
  int rem = idx - i * (DDIM * 3);
  int d = rem / 3, m = rem - d * 3;
  int token = OFFS[i + 1] - 3 + m;
  out2[idx] = x[(size_t)token * DDIM + d];
}

// ---------------------------------------------------------------------------
extern "C" void kernel_launch(void* const* d_in, const int* in_sizes, int n_in,
                              void* d_out, int out_size, void* d_ws, size_t ws_size,
                              hipStream_t stream) {
  (void)in_sizes; (void)n_in; (void)out_size; (void)ws_size;
  const float* x  = (const float*)d_in[0];
  const float* cs = (const float*)d_in[1];
  const float* gi = (const float*)d_in[2];
  const float* w1 = (const float*)d_in[4];
  const float* w2 = (const float*)d_in[5];
  const float* b2 = (const float*)d_in[6];
  float* out = (float*)d_out;

  char* ws = (char*)d_ws;
  u16* w2T = (u16*)ws;                        // [8192][256] bf16 : 4,194,304 B
  u16* w1T = (u16*)(ws + 4194304);            // [256][2048] bf16 : 1,048,576 B
  u16* h   = (u16*)(ws + 4194304 + 1048576);  // [9728][256] bf16 swizzled : 4,980,736 B

  transpose_bf16_k<<<dim3(8192 / 64, 256 / 64), 256, 0, stream>>>(w2, w2T, GHN, DDIM * 4);
  transpose_bf16_k<<<dim3(256 / 64, 2048 / 64), 256, 0, stream>>>(w1, w1T, DDIM, GHN);
  gemm1_silu<<<T_TOT / 32, 256, 0, stream>>>(gi, w1T, h);
  // each block: 4 waves x 16 cols = 64 of the D*K = 8192 kern columns -> 128 y-blocks
  gemm2_conv<<<dim3(T_TOT / 256, (DDIM * 4) / 64), 256, 0, stream>>>(h, w2T, b2, x, cs, out);
  tail_state<<<(NSEQ * DDIM * 3) / 256, 256, 0, stream>>>(x, out + (size_t)T_TOT * DDIM);
}